// Round 14
// baseline (143.115 us; speedup 1.0000x reference)
//
#include <hip/hip_runtime.h>

#define M_DIM 64
#define K_DIM 8192
#define N_DIM 10240
#define KSPLIT 8
#define KBLK (K_DIM / KSPLIT)    // 1024 k per block
#define KSTEP 128                 // k per chunk (ints)
#define NCHUNK (KBLK / KSTEP)     // 8
#define NTILE 64                  // n cols per block (4 waves x 16)

typedef __attribute__((ext_vector_type(8))) short short8;
typedef __attribute__((ext_vector_type(4))) float f32x4;
typedef __attribute__((ext_vector_type(4))) int i32x4;

// exact for integer-valued floats |v| <= 127
static __device__ __forceinline__ ushort f2bf_trunc(float f) {
    return (ushort)(__float_as_uint(f) >> 16);
}

// ---------------- Kernel 1: per-token dynamic int8 quantization ----------------
// (verbatim — verified rounds 5/11/13)
__global__ __launch_bounds__(256) void quant_kernel(
    const float* __restrict__ x,
    ushort* __restrict__ xq,
    float* __restrict__ xscale) {
    const int m = blockIdx.x;
    const int tid = threadIdx.x;
    const float4* xrow = (const float4*)(x + m * K_DIM);
    float4 c[8];
    float mx = 0.f;
#pragma unroll
    for (int i = 0; i < 8; ++i) {
        c[i] = xrow[i * 256 + tid];
        mx = fmaxf(mx, fmaxf(fmaxf(fabsf(c[i].x), fabsf(c[i].y)),
                             fmaxf(fabsf(c[i].z), fabsf(c[i].w))));
    }
#pragma unroll
    for (int off = 32; off; off >>= 1) mx = fmaxf(mx, __shfl_xor(mx, off));
    __shared__ float wmax[4];
    if ((tid & 63) == 0) wmax[tid >> 6] = mx;
    __syncthreads();
    mx = fmaxf(fmaxf(wmax[0], wmax[1]), fmaxf(wmax[2], wmax[3]));
    const float s = mx / 127.0f;
    if (tid == 0) xscale[m] = s;

    ushort4* qrow = (ushort4*)(xq + m * K_DIM);
#pragma unroll
    for (int i = 0; i < 8; ++i) {
        float q0 = fminf(fmaxf(rintf(c[i].x / s), -127.f), 127.f);
        float q1 = fminf(fmaxf(rintf(c[i].y / s), -127.f), 127.f);
        float q2 = fminf(fmaxf(rintf(c[i].z / s), -127.f), 127.f);
        float q3 = fminf(fmaxf(rintf(c[i].w / s), -127.f), 127.f);
        ushort4 o;
        o.x = f2bf_trunc(q0);
        o.y = f2bf_trunc(q1);
        o.z = f2bf_trunc(q2);
        o.w = f2bf_trunc(q3);
        qrow[i * 256 + tid] = o;
    }
}

// ---------------- Kernel 2: single-buffer 32 KB LDS -> 5 blocks/CU -------------
// grid (160, 8), 4 waves. Same dataflow/swizzle/fragment law as verified r11,
// with the chunk dbuf removed (loop was logically single-buffered anyway) and
// the loop reordered to {publish-sync; ISSUE(c+1); COMPUTE(c); free-sync;
// WRITE(c+1)} so the next chunk streams during compute+syncs. 32 KB LDS makes
// ALL 5 blocks/CU co-resident (20 waves/CU): no rounds, no dispatch gaps,
// no solo-block tail.
__global__ __launch_bounds__(256, 5) void gemm_kernel(
    const ushort* __restrict__ xq,   // bf16 bits [64, 8192]
    const int* __restrict__ W,       // int32 [10240, 8192], |v| <= 127
    float* __restrict__ partials) {  // f32 [KSPLIT][64][10240]
    const int tid = threadIdx.x;
    const int w = tid >> 6;
    const int lane = tid & 63;
    const int r16 = lane & 15;
    const int kgrp = lane >> 4;
    const int n0 = blockIdx.x * NTILE;
    const int kb = blockIdx.y;
    const int k0 = kb * KBLK;

    __shared__ __align__(16) ushort Abuf[M_DIM * KSTEP];   // 16 KB
    __shared__ __align__(16) ushort Bbuf[NTILE * KSTEP];   // 16 KB

    i32x4 aB[8];    // W staging: 8 instrs x (2 rows x 512B) contiguous
    short8 aA[4];   // A staging: 4 instrs x (4 rows x 256B) contiguous

#define ISSUE_B(c)                                                             \
    {                                                                          \
        const int* base = W + k0 + (c) * KSTEP + (lane & 31) * 4;              \
        _Pragma("unroll") for (int i = 0; i < 8; ++i) {                        \
            const int row = n0 + w * 16 + i * 2 + (lane >> 5);                 \
            aB[i] = *(const i32x4*)(base + (size_t)row * K_DIM);               \
        }                                                                      \
    }
#define ISSUE_A(c)                                                             \
    {                                                                          \
        const ushort* base = xq + k0 + (c) * KSTEP + (lane & 15) * 8;          \
        _Pragma("unroll") for (int i = 0; i < 4; ++i) {                        \
            const int row = w * 16 + i * 4 + (lane >> 4);                      \
            aA[i] = *(const short8*)(base + row * K_DIM);                      \
        }                                                                      \
    }
#define WRITE_A()                                                              \
    {                                                                          \
        _Pragma("unroll") for (int i = 0; i < 4; ++i) {                        \
            const int row = w * 16 + i * 4 + (lane >> 4);                      \
            const int off = ((lane & 15) * 16) ^ ((row & 7) << 4);             \
            *(short8*)((char*)&Abuf[row * KSTEP] + off) = aA[i];               \
        }                                                                      \
    }
#define WRITE_B()                                                              \
    {                                                                          \
        _Pragma("unroll") for (int i = 0; i < 8; ++i) {                        \
            const int row = w * 16 + i * 2 + (lane >> 5);                      \
            ushort4 h;                                                         \
            h.x = f2bf_trunc((float)aB[i][0]);                                 \
            h.y = f2bf_trunc((float)aB[i][1]);                                 \
            h.z = f2bf_trunc((float)aB[i][2]);                                 \
            h.w = f2bf_trunc((float)aB[i][3]);                                 \
            const int off = ((lane & 31) * 8) ^ ((row & 7) << 4);              \
            *(ushort4*)((char*)&Bbuf[row * KSTEP] + off) = h;                  \
        }                                                                      \
    }
#define COMPUTE()                                                              \
    {                                                                          \
        _Pragma("unroll") for (int ks = 0; ks < 4; ++ks) {                     \
            const int swz = (ks * 64 + kgrp * 16) ^ ((r16 & 7) << 4);          \
            short8 bfrag = *(const short8*)(                                   \
                (char*)&Bbuf[(w * 16 + r16) * KSTEP] + swz);                   \
            _Pragma("unroll") for (int mt = 0; mt < 4; ++mt) {                 \
                short8 afrag = *(const short8*)(                               \
                    (char*)&Abuf[(mt * 16 + r16) * KSTEP] + swz);              \
                acc[mt] = __builtin_amdgcn_mfma_f32_16x16x32_bf16(             \
                    afrag, bfrag, acc[mt], 0, 0, 0);                           \
            }                                                                  \
        }                                                                      \
    }

    f32x4 acc[4];
#pragma unroll
    for (int i = 0; i < 4; ++i) acc[i] = (f32x4){0.f, 0.f, 0.f, 0.f};

    // prologue: chunk 0 staged and published; chunk 1 issued
    ISSUE_B(0)
    ISSUE_A(0)
    WRITE_A()
    WRITE_B()
    __syncthreads();          // publish chunk 0

#pragma unroll
    for (int c = 0; c < NCHUNK - 1; ++c) {
        ISSUE_B(c + 1)        // streams during COMPUTE + syncs
        ISSUE_A(c + 1)
        COMPUTE();
        __syncthreads();      // all waves done reading chunk c
        WRITE_A()             // waits chunk c+1 (mostly delivered by now)
        WRITE_B()
        __syncthreads();      // publish chunk c+1
    }
    COMPUTE();

    // epilogue: C via LDS for coalesced partials write (r11-verbatim law)
    __syncthreads();
    float* Cl = (float*)&Abuf[0];  // [64 m][64 n] f32 = 16 KB (fits Abuf)
#pragma unroll
    for (int mt = 0; mt < 4; ++mt)
#pragma unroll
        for (int j = 0; j < 4; ++j)
            Cl[(mt * 16 + kgrp * 4 + j) * 64 + w * 16 + r16] = acc[mt][j];
    __syncthreads();
    float* pb = partials + (size_t)kb * (M_DIM * N_DIM);
#pragma unroll
    for (int i = 0; i < 4; ++i) {
        const int idx = tid + 256 * i;
        const int m = idx >> 4;
        const int ch = idx & 15;
        *(f32x4*)(pb + m * N_DIM + n0 + ch * 4) = ((const f32x4*)Cl)[idx];
    }
#undef ISSUE_B
#undef ISSUE_A
#undef WRITE_A
#undef WRITE_B
#undef COMPUTE
}

// ---------------- Kernel 3: split-K reduce + dequant + bias --------------------
// (verbatim — verified rounds 5/11/13)
__global__ __launch_bounds__(256) void reduce_kernel(
    const float* __restrict__ partials,
    const float* __restrict__ xscale,
    const float* __restrict__ wscale,
    const float* __restrict__ bias,
    float* __restrict__ out) {
    const int idx = blockIdx.x * 256 + threadIdx.x;  // 0 .. 64*2560-1
    const int m = idx / (N_DIM / 4);
    const int c = idx - m * (N_DIM / 4);
    const f32x4* P = (const f32x4*)partials;
    f32x4 s = (f32x4){0.f, 0.f, 0.f, 0.f};
#pragma unroll
    for (int p = 0; p < KSPLIT; ++p)
        s += P[((size_t)p * M_DIM + m) * (N_DIM / 4) + c];
    f32x4 ws = ((const f32x4*)wscale)[c];
    f32x4 bs = ((const f32x4*)bias)[c];
    const float xs = xscale[m];
    ((f32x4*)out)[idx] = s * xs * ws + bs;
}

extern "C" void kernel_launch(void* const* d_in, const int* in_sizes, int n_in,
                              void* d_out, int out_size, void* d_ws, size_t ws_size,
                              hipStream_t stream) {
    const float* x = (const float*)d_in[0];
    const int* W = (const int*)d_in[1];
    const float* wscale = (const float*)d_in[2];
    const float* bias = (const float*)d_in[3];
    float* out = (float*)d_out;

    float* xscale = (float*)d_ws;                       // 256 B
    ushort* xq = (ushort*)((char*)d_ws + 4096);         // 1 MB
    float* partials = (float*)((char*)d_ws + 2097152);  // 21 MB

    quant_kernel<<<M_DIM, 256, 0, stream>>>(x, xq, xscale);
    gemm_kernel<<<dim3(N_DIM / NTILE, KSPLIT), 256, 0, stream>>>(xq, W, partials);
    reduce_kernel<<<(M_DIM * N_DIM / 4) / 256, 256, 0, stream>>>(
        partials, xscale, wscale, bias, out);
}

// Round 15
// 91.802 us; speedup vs baseline: 1.5590x; 1.5590x over previous
//
#include <hip/hip_runtime.h>

#define M_DIM 64
#define K_DIM 8192
#define N_DIM 10240
#define KSPLIT 2
#define KBLK (K_DIM / KSPLIT)    // 4096 k per block
#define KSTEP 128                 // k per chunk (ints)
#define NCHUNK (KBLK / KSTEP)     // 32
#define NTILE 16                  // n rows per block (one 16-col tile)

typedef __attribute__((ext_vector_type(8))) short short8;
typedef __attribute__((ext_vector_type(4))) float f32x4;
typedef __attribute__((ext_vector_type(4))) int i32x4;

// exact for integer-valued floats |v| <= 127
static __device__ __forceinline__ ushort f2bf_trunc(float f) {
    return (ushort)(__float_as_uint(f) >> 16);
}

// ---------------- Kernel 1: per-token dynamic int8 quantization ----------------
// (verbatim — verified rounds 5/11/13)
__global__ __launch_bounds__(256) void quant_kernel(
    const float* __restrict__ x,
    ushort* __restrict__ xq,
    float* __restrict__ xscale) {
    const int m = blockIdx.x;
    const int tid = threadIdx.x;
    const float4* xrow = (const float4*)(x + m * K_DIM);
    float4 c[8];
    float mx = 0.f;
#pragma unroll
    for (int i = 0; i < 8; ++i) {
        c[i] = xrow[i * 256 + tid];
        mx = fmaxf(mx, fmaxf(fmaxf(fabsf(c[i].x), fabsf(c[i].y)),
                             fmaxf(fabsf(c[i].z), fabsf(c[i].w))));
    }
#pragma unroll
    for (int off = 32; off; off >>= 1) mx = fmaxf(mx, __shfl_xor(mx, off));
    __shared__ float wmax[4];
    if ((tid & 63) == 0) wmax[tid >> 6] = mx;
    __syncthreads();
    mx = fmaxf(fmaxf(wmax[0], wmax[1]), fmaxf(wmax[2], wmax[3]));
    const float s = mx / 127.0f;
    if (tid == 0) xscale[m] = s;

    ushort4* qrow = (ushort4*)(xq + m * K_DIM);
#pragma unroll
    for (int i = 0; i < 8; ++i) {
        float q0 = fminf(fmaxf(rintf(c[i].x / s), -127.f), 127.f);
        float q1 = fminf(fmaxf(rintf(c[i].y / s), -127.f), 127.f);
        float q2 = fminf(fmaxf(rintf(c[i].z / s), -127.f), 127.f);
        float q3 = fminf(fmaxf(rintf(c[i].w / s), -127.f), 127.f);
        ushort4 o;
        o.x = f2bf_trunc(q0);
        o.y = f2bf_trunc(q1);
        o.z = f2bf_trunc(q2);
        o.w = f2bf_trunc(q3);
        qrow[i * 256 + tid] = o;
    }
}

// ---------------- Kernel 2: N-thin blocks, sequential W streams ----------------
// grid (640, 2), 4 waves, 40 KB LDS -> 4 blocks/CU resident. Each block owns
// 16 W rows x K/2: every row is ONE sequential DRAM stream (32 x 512B chunks
// back-to-back). A-path, swizzle law, and barrier discipline verbatim r11.
// Per wave: one 16m x 16n output tile (acc = 4 VGPR). KSPLIT=2 partials.
__global__ __launch_bounds__(256, 4) void gemm_kernel(
    const ushort* __restrict__ xq,   // bf16 bits [64, 8192]
    const int* __restrict__ W,       // int32 [10240, 8192], |v| <= 127
    float* __restrict__ partials) {  // f32 [KSPLIT][64][10240]
    const int tid = threadIdx.x;
    const int w = tid >> 6;
    const int lane = tid & 63;
    const int r16 = lane & 15;
    const int kgrp = lane >> 4;
    const int n0 = blockIdx.x * NTILE;
    const int kb = blockIdx.y;
    const int k0 = kb * KBLK;

    __shared__ __align__(16) ushort Abuf[2][M_DIM * KSTEP];   // 2 x 16 KB
    __shared__ __align__(16) ushort Bbuf[2][NTILE * KSTEP];   // 2 x 4 KB

    i32x4 aB[2];    // W staging: 2 x 16B per thread (32B contiguous of one row)
    short8 aA[4];   // A staging: r11-verbatim layout

#define ISSUE_B(c)                                                             \
    {                                                                          \
        const int* base =                                                      \
            W + k0 + (c) * KSTEP + (size_t)(n0 + (tid >> 4)) * K_DIM +         \
            (tid & 15) * 8;                                                    \
        aB[0] = *(const i32x4*)(base);                                         \
        aB[1] = *(const i32x4*)(base + 4);                                     \
    }
#define ISSUE_A(c)                                                             \
    {                                                                          \
        const ushort* base = xq + k0 + (c) * KSTEP + (lane & 15) * 8;          \
        _Pragma("unroll") for (int i = 0; i < 4; ++i) {                        \
            const int row = w * 16 + i * 4 + (lane >> 4);                      \
            aA[i] = *(const short8*)(base + row * K_DIM);                      \
        }                                                                      \
    }
#define WRITE_A(bufi)                                                          \
    {                                                                          \
        _Pragma("unroll") for (int i = 0; i < 4; ++i) {                        \
            const int row = w * 16 + i * 4 + (lane >> 4);                      \
            const int off = ((lane & 15) * 16) ^ ((row & 7) << 4);             \
            *(short8*)((char*)&Abuf[bufi][row * KSTEP] + off) = aA[i];         \
        }                                                                      \
    }
#define WRITE_B(bufi)                                                          \
    {                                                                          \
        const int row = tid >> 4;                                              \
        short8 h;                                                              \
        _Pragma("unroll") for (int i = 0; i < 4; ++i) {                        \
            h[i] = (short)f2bf_trunc((float)aB[0][i]);                         \
            h[4 + i] = (short)f2bf_trunc((float)aB[1][i]);                     \
        }                                                                      \
        const int off = ((tid & 15) * 16) ^ ((row & 7) << 4);                  \
        *(short8*)((char*)&Bbuf[bufi][row * KSTEP] + off) = h;                 \
    }
#define COMPUTE(bufi)                                                          \
    {                                                                          \
        _Pragma("unroll") for (int ks = 0; ks < 4; ++ks) {                     \
            const int swz = (ks * 64 + kgrp * 16) ^ ((r16 & 7) << 4);          \
            short8 bfrag = *(const short8*)(                                   \
                (char*)&Bbuf[bufi][r16 * KSTEP] + swz);                        \
            short8 afrag = *(const short8*)(                                   \
                (char*)&Abuf[bufi][(w * 16 + r16) * KSTEP] + swz);             \
            acc = __builtin_amdgcn_mfma_f32_16x16x32_bf16(                     \
                afrag, bfrag, acc, 0, 0, 0);                                   \
        }                                                                      \
    }

    f32x4 acc = (f32x4){0.f, 0.f, 0.f, 0.f};

    // prologue: chunk 0 staged; chunk 1 in flight (r11 verified pattern)
    ISSUE_B(0)
    ISSUE_A(0)
    WRITE_A(0)
    WRITE_B(0)
    __syncthreads();
    ISSUE_B(1)
    ISSUE_A(1)

#pragma unroll
    for (int c = 0; c < NCHUNK; ++c) {
        COMPUTE(c & 1);
        if (c < NCHUNK - 1) {
            __syncthreads();  // all waves done reading buf (c+1)&1's old data
            WRITE_A((c + 1) & 1)
            WRITE_B((c + 1) & 1)
            if (c + 2 < NCHUNK) {
                ISSUE_B(c + 2)
                ISSUE_A(c + 2)
            }
            __syncthreads();  // new chunk visible
        }
    }

    // epilogue: per-wave 16x16 tile direct store (lanes 0-15 consecutive n)
    float* pb = partials + (size_t)kb * (M_DIM * N_DIM);
#pragma unroll
    for (int j = 0; j < 4; ++j) {
        const int m = w * 16 + kgrp * 4 + j;
        pb[m * N_DIM + n0 + r16] = acc[j];
    }
#undef ISSUE_B
#undef ISSUE_A
#undef WRITE_A
#undef WRITE_B
#undef COMPUTE
}

// ---------------- Kernel 3: split-K reduce + dequant + bias --------------------
__global__ __launch_bounds__(256) void reduce_kernel(
    const float* __restrict__ partials,
    const float* __restrict__ xscale,
    const float* __restrict__ wscale,
    const float* __restrict__ bias,
    float* __restrict__ out) {
    const int idx = blockIdx.x * 256 + threadIdx.x;  // 0 .. 64*2560-1
    const int m = idx / (N_DIM / 4);
    const int c = idx - m * (N_DIM / 4);
    const f32x4* P = (const f32x4*)partials;
    f32x4 s = P[idx] + P[(M_DIM * N_DIM / 4) + idx];
    f32x4 ws = ((const f32x4*)wscale)[c];
    f32x4 bs = ((const f32x4*)bias)[c];
    const float xs = xscale[m];
    ((f32x4*)out)[idx] = s * xs * ws + bs;
}

extern "C" void kernel_launch(void* const* d_in, const int* in_sizes, int n_in,
                              void* d_out, int out_size, void* d_ws, size_t ws_size,
                              hipStream_t stream) {
    const float* x = (const float*)d_in[0];
    const int* W = (const int*)d_in[1];
    const float* wscale = (const float*)d_in[2];
    const float* bias = (const float*)d_in[3];
    float* out = (float*)d_out;

    float* xscale = (float*)d_ws;                       // 256 B
    ushort* xq = (ushort*)((char*)d_ws + 4096);         // 1 MB
    float* partials = (float*)((char*)d_ws + 2097152);  // 5.24 MB

    quant_kernel<<<M_DIM, 256, 0, stream>>>(x, xq, xscale);
    gemm_kernel<<<dim3(N_DIM / NTILE, KSPLIT), 256, 0, stream>>>(xq, W, partials);
    reduce_kernel<<<(M_DIM * N_DIM / 4) / 256, 256, 0, stream>>>(
        partials, xscale, wscale, bias, out);
}

// Round 16
// 82.433 us; speedup vs baseline: 1.7361x; 1.1137x over previous
//
#include <hip/hip_runtime.h>

#define M_DIM 64
#define K_DIM 8192
#define N_DIM 10240
#define KSPLIT 8
#define KBLK (K_DIM / KSPLIT)    // 1024 k per block
#define KSTEP 128                 // k per LDS chunk (ints)
#define NTILE 64                  // n cols per block (4 waves x 16)
#define BUFB (NTILE * KSTEP * 2)  // bytes per LDS buffer half (16 KB)

typedef __attribute__((ext_vector_type(8))) short short8;
typedef __attribute__((ext_vector_type(4))) float f32x4;
typedef __attribute__((ext_vector_type(4))) int i32x4;

// exact for integer-valued floats |v| <= 127
static __device__ __forceinline__ ushort f2bf_trunc(float f) {
    return (ushort)(__float_as_uint(f) >> 16);
}

// ---------------- Kernel 1: per-token dynamic int8 quantization ----------------
// (verbatim — verified rounds 5/11/13)
__global__ __launch_bounds__(256) void quant_kernel(
    const float* __restrict__ x,
    ushort* __restrict__ xq,
    float* __restrict__ xscale) {
    const int m = blockIdx.x;
    const int tid = threadIdx.x;
    const float4* xrow = (const float4*)(x + m * K_DIM);
    float4 c[8];
    float mx = 0.f;
#pragma unroll
    for (int i = 0; i < 8; ++i) {
        c[i] = xrow[i * 256 + tid];
        mx = fmaxf(mx, fmaxf(fmaxf(fabsf(c[i].x), fabsf(c[i].y)),
                             fmaxf(fabsf(c[i].z), fabsf(c[i].w))));
    }
#pragma unroll
    for (int off = 32; off; off >>= 1) mx = fmaxf(mx, __shfl_xor(mx, off));
    __shared__ float wmax[4];
    if ((tid & 63) == 0) wmax[tid >> 6] = mx;
    __syncthreads();
    mx = fmaxf(fmaxf(wmax[0], wmax[1]), fmaxf(wmax[2], wmax[3]));
    const float s = mx / 127.0f;
    if (tid == 0) xscale[m] = s;

    ushort4* qrow = (ushort4*)(xq + m * K_DIM);
#pragma unroll
    for (int i = 0; i < 8; ++i) {
        float q0 = fminf(fmaxf(rintf(c[i].x / s), -127.f), 127.f);
        float q1 = fminf(fmaxf(rintf(c[i].y / s), -127.f), 127.f);
        float q2 = fminf(fmaxf(rintf(c[i].z / s), -127.f), 127.f);
        float q3 = fminf(fmaxf(rintf(c[i].w / s), -127.f), 127.f);
        ushort4 o;
        o.x = f2bf_trunc(q0);
        o.y = f2bf_trunc(q1);
        o.z = f2bf_trunc(q2);
        o.w = f2bf_trunc(q3);
        qrow[i * 256 + tid] = o;
    }
}

// ---------------- Kernel 2: granule-paired LDS pipeline + NT W stream ----------
// r13 verbatim EXCEPT: W loads use __builtin_nontemporal_load so the 335 MB
// one-shot W stream does not evict the 1 MB/XCD-resident xq from L2 —
// A-re-reads (164 MB logical across blocks) stay L2-hits instead of thrashing.
__global__ __launch_bounds__(256, 2) void gemm_kernel(
    const ushort* __restrict__ xq,   // bf16 bits [64, 8192]
    const int* __restrict__ W,       // int32 [10240, 8192], |v| <= 127
    float* __restrict__ partials) {  // f32 [KSPLIT][64][10240]
    const int tid = threadIdx.x;
    const int w = tid >> 6;
    const int lane = tid & 63;
    const int r16 = lane & 15;
    const int kgrp = lane >> 4;
    const int n0 = blockIdx.x * NTILE;
    const int kb = blockIdx.y;
    const int k0 = kb * KBLK;

    __shared__ __align__(16) ushort Abuf[2][NTILE * KSTEP];  // 2 x 16 KB
    __shared__ __align__(16) ushort Bbuf[2][NTILE * KSTEP];  // 2 x 16 KB

    i32x4 aB[16];   // W granule: 16 instrs x 1KB-contiguous (one row x 256 ints)
    short8 aA[8];   // A granule: 8 instrs x 1KB (2 rows x 256 ushorts)

#define ISSUE_B2(g)                                                            \
    {                                                                          \
        const int* base = W + k0 + (g) * 256 + lane * 4;                       \
        _Pragma("unroll") for (int i = 0; i < 16; ++i) {                       \
            aB[i] = __builtin_nontemporal_load(                                \
                (const i32x4*)(base + (size_t)(n0 + w * 16 + i) * K_DIM));     \
        }                                                                      \
    }
#define ISSUE_A2(g)                                                            \
    {                                                                          \
        const ushort* base = xq + k0 + (g) * 256 + (lane & 31) * 8;            \
        _Pragma("unroll") for (int i = 0; i < 8; ++i) {                        \
            const int row = w * 16 + i * 2 + (lane >> 5);                      \
            aA[i] = *(const short8*)(base + row * K_DIM);                      \
        }                                                                      \
    }
// writes BOTH chunks of the granule: lane half selects destination buffer
#define WRITE_B2()                                                             \
    {                                                                          \
        char* bb = (char*)&Bbuf[0][0] + (lane >> 5) * BUFB;                    \
        _Pragma("unroll") for (int i = 0; i < 16; ++i) {                       \
            const int row = w * 16 + i;                                        \
            ushort4 h;                                                         \
            h.x = f2bf_trunc((float)aB[i][0]);                                 \
            h.y = f2bf_trunc((float)aB[i][1]);                                 \
            h.z = f2bf_trunc((float)aB[i][2]);                                 \
            h.w = f2bf_trunc((float)aB[i][3]);                                 \
            const int off = ((lane & 31) * 8) ^ ((row & 7) << 4);              \
            *(ushort4*)(bb + row * 256 + off) = h;                             \
        }                                                                      \
    }
#define WRITE_A2()                                                             \
    {                                                                          \
        char* ab = (char*)&Abuf[0][0] + ((lane & 31) >> 4) * BUFB;             \
        _Pragma("unroll") for (int i = 0; i < 8; ++i) {                        \
            const int row = w * 16 + i * 2 + (lane >> 5);                      \
            const int off = ((lane & 15) * 16) ^ ((row & 7) << 4);             \
            *(short8*)(ab + row * 256 + off) = aA[i];                          \
        }                                                                      \
    }
#define COMPUTE(bufi)                                                          \
    {                                                                          \
        _Pragma("unroll") for (int ks = 0; ks < 4; ++ks) {                     \
            const int swz = (ks * 64 + kgrp * 16) ^ ((r16 & 7) << 4);          \
            short8 bfrag = *(const short8*)(                                   \
                (char*)&Bbuf[bufi][(w * 16 + r16) * KSTEP] + swz);             \
            _Pragma("unroll") for (int mt = 0; mt < 4; ++mt) {                 \
                short8 afrag = *(const short8*)(                               \
                    (char*)&Abuf[bufi][(mt * 16 + r16) * KSTEP] + swz);        \
                acc[mt] = __builtin_amdgcn_mfma_f32_16x16x32_bf16(             \
                    afrag, bfrag, acc[mt], 0, 0, 0);                           \
            }                                                                  \
        }                                                                      \
    }

    f32x4 acc[4];
#pragma unroll
    for (int i = 0; i < 4; ++i) acc[i] = (f32x4){0.f, 0.f, 0.f, 0.f};

    // granule 0
    ISSUE_B2(0)
    ISSUE_A2(0)
    WRITE_B2()
    WRITE_A2()
    __syncthreads();
    ISSUE_B2(1)
    ISSUE_A2(1)
    COMPUTE(0)
    COMPUTE(1)
    __syncthreads();

    // granule 1
    WRITE_B2()
    WRITE_A2()
    ISSUE_B2(2)
    ISSUE_A2(2)
    __syncthreads();
    COMPUTE(0)
    COMPUTE(1)
    __syncthreads();

    // granule 2
    WRITE_B2()
    WRITE_A2()
    ISSUE_B2(3)
    ISSUE_A2(3)
    __syncthreads();
    COMPUTE(0)
    COMPUTE(1)
    __syncthreads();

    // granule 3
    WRITE_B2()
    WRITE_A2()
    __syncthreads();
    COMPUTE(0)
    COMPUTE(1)

    // epilogue: C via LDS for coalesced partials write (r11/r13 verbatim)
    __syncthreads();
    float* Cl = (float*)&Abuf[0][0];  // [64 m][64 n] f32 = 16 KB
#pragma unroll
    for (int mt = 0; mt < 4; ++mt)
#pragma unroll
        for (int j = 0; j < 4; ++j)
            Cl[(mt * 16 + kgrp * 4 + j) * 64 + w * 16 + r16] = acc[mt][j];
    __syncthreads();
    float* pb = partials + (size_t)kb * (M_DIM * N_DIM);
#pragma unroll
    for (int i = 0; i < 4; ++i) {
        const int idx = tid + 256 * i;
        const int m = idx >> 4;
        const int ch = idx & 15;
        *(f32x4*)(pb + m * N_DIM + n0 + ch * 4) = ((const f32x4*)Cl)[idx];
    }
#undef ISSUE_B2
#undef ISSUE_A2
#undef WRITE_A2
#undef WRITE_B2
#undef COMPUTE
}

// ---------------- Kernel 3: split-K reduce + dequant + bias --------------------
// (verbatim — verified rounds 5/11/13)
__global__ __launch_bounds__(256) void reduce_kernel(
    const float* __restrict__ partials,
    const float* __restrict__ xscale,
    const float* __restrict__ wscale,
    const float* __restrict__ bias,
    float* __restrict__ out) {
    const int idx = blockIdx.x * 256 + threadIdx.x;  // 0 .. 64*2560-1
    const int m = idx / (N_DIM / 4);
    const int c = idx - m * (N_DIM / 4);
    const f32x4* P = (const f32x4*)partials;
    f32x4 s = (f32x4){0.f, 0.f, 0.f, 0.f};
#pragma unroll
    for (int p = 0; p < KSPLIT; ++p)
        s += P[((size_t)p * M_DIM + m) * (N_DIM / 4) + c];
    f32x4 ws = ((const f32x4*)wscale)[c];
    f32x4 bs = ((const f32x4*)bias)[c];
    const float xs = xscale[m];
    ((f32x4*)out)[idx] = s * xs * ws + bs;
}

extern "C" void kernel_launch(void* const* d_in, const int* in_sizes, int n_in,
                              void* d_out, int out_size, void* d_ws, size_t ws_size,
                              hipStream_t stream) {
    const float* x = (const float*)d_in[0];
    const int* W = (const int*)d_in[1];
    const float* wscale = (const float*)d_in[2];
    const float* bias = (const float*)d_in[3];
    float* out = (float*)d_out;

    float* xscale = (float*)d_ws;                       // 256 B
    ushort* xq = (ushort*)((char*)d_ws + 4096);         // 1 MB
    float* partials = (float*)((char*)d_ws + 2097152);  // 21 MB

    quant_kernel<<<M_DIM, 256, 0, stream>>>(x, xq, xscale);
    gemm_kernel<<<dim3(N_DIM / NTILE, KSPLIT), 256, 0, stream>>>(xq, W, partials);
    reduce_kernel<<<(M_DIM * N_DIM / 4) / 256, 256, 0, stream>>>(
        partials, xscale, wscale, bias, out);
}

// Round 17
// 82.102 us; speedup vs baseline: 1.7431x; 1.0040x over previous
//
#include <hip/hip_runtime.h>

#define M_DIM 64
#define K_DIM 8192
#define N_DIM 10240
#define KSPLIT 4
#define KBLK (K_DIM / KSPLIT)    // 2048 k per block
#define KSTEP 128                 // k per LDS chunk (ints)
#define NGRAN (KBLK / 256)        // 8 granules of 2 chunks
#define NTILE 64                  // n cols per block (4 waves x 16)
#define BUFB (NTILE * KSTEP * 2)  // bytes per LDS buffer half (16 KB)

typedef __attribute__((ext_vector_type(8))) short short8;
typedef __attribute__((ext_vector_type(4))) float f32x4;
typedef __attribute__((ext_vector_type(4))) int i32x4;

// exact for integer-valued floats |v| <= 127
static __device__ __forceinline__ ushort f2bf_trunc(float f) {
    return (ushort)(__float_as_uint(f) >> 16);
}

// ---------------- Kernel 1: per-token dynamic int8 quantization ----------------
// (verbatim — verified rounds 5/11/13/16)
__global__ __launch_bounds__(256) void quant_kernel(
    const float* __restrict__ x,
    ushort* __restrict__ xq,
    float* __restrict__ xscale) {
    const int m = blockIdx.x;
    const int tid = threadIdx.x;
    const float4* xrow = (const float4*)(x + m * K_DIM);
    float4 c[8];
    float mx = 0.f;
#pragma unroll
    for (int i = 0; i < 8; ++i) {
        c[i] = xrow[i * 256 + tid];
        mx = fmaxf(mx, fmaxf(fmaxf(fabsf(c[i].x), fabsf(c[i].y)),
                             fmaxf(fabsf(c[i].z), fabsf(c[i].w))));
    }
#pragma unroll
    for (int off = 32; off; off >>= 1) mx = fmaxf(mx, __shfl_xor(mx, off));
    __shared__ float wmax[4];
    if ((tid & 63) == 0) wmax[tid >> 6] = mx;
    __syncthreads();
    mx = fmaxf(fmaxf(wmax[0], wmax[1]), fmaxf(wmax[2], wmax[3]));
    const float s = mx / 127.0f;
    if (tid == 0) xscale[m] = s;

    ushort4* qrow = (ushort4*)(xq + m * K_DIM);
#pragma unroll
    for (int i = 0; i < 8; ++i) {
        float q0 = fminf(fmaxf(rintf(c[i].x / s), -127.f), 127.f);
        float q1 = fminf(fmaxf(rintf(c[i].y / s), -127.f), 127.f);
        float q2 = fminf(fmaxf(rintf(c[i].z / s), -127.f), 127.f);
        float q3 = fminf(fmaxf(rintf(c[i].w / s), -127.f), 127.f);
        ushort4 o;
        o.x = f2bf_trunc(q0);
        o.y = f2bf_trunc(q1);
        o.z = f2bf_trunc(q2);
        o.w = f2bf_trunc(q3);
        qrow[i * 256 + tid] = o;
    }
}

// ---------------- Kernel 2: r16 structure, KSPLIT 8 -> 4 -----------------------
// grid (160, 4), 4 waves, 64 KB LDS -> 2 blocks/CU. Identical granule-paired
// pipeline + NT W stream as verified r16; only the K-split changed: halves
// partials traffic (42 -> 21 MB round-trip) and block-prologue count.
__global__ __launch_bounds__(256, 2) void gemm_kernel(
    const ushort* __restrict__ xq,   // bf16 bits [64, 8192]
    const int* __restrict__ W,       // int32 [10240, 8192], |v| <= 127
    float* __restrict__ partials) {  // f32 [KSPLIT][64][10240]
    const int tid = threadIdx.x;
    const int w = tid >> 6;
    const int lane = tid & 63;
    const int r16 = lane & 15;
    const int kgrp = lane >> 4;
    const int n0 = blockIdx.x * NTILE;
    const int kb = blockIdx.y;
    const int k0 = kb * KBLK;

    __shared__ __align__(16) ushort Abuf[2][NTILE * KSTEP];  // 2 x 16 KB
    __shared__ __align__(16) ushort Bbuf[2][NTILE * KSTEP];  // 2 x 16 KB

    i32x4 aB[16];   // W granule: 16 instrs x 1KB-contiguous (one row x 256 ints)
    short8 aA[8];   // A granule: 8 instrs x 1KB (2 rows x 256 ushorts)

#define ISSUE_B2(g)                                                            \
    {                                                                          \
        const int* base = W + k0 + (g) * 256 + lane * 4;                       \
        _Pragma("unroll") for (int i = 0; i < 16; ++i) {                       \
            aB[i] = __builtin_nontemporal_load(                                \
                (const i32x4*)(base + (size_t)(n0 + w * 16 + i) * K_DIM));     \
        }                                                                      \
    }
#define ISSUE_A2(g)                                                            \
    {                                                                          \
        const ushort* base = xq + k0 + (g) * 256 + (lane & 31) * 8;            \
        _Pragma("unroll") for (int i = 0; i < 8; ++i) {                        \
            const int row = w * 16 + i * 2 + (lane >> 5);                      \
            aA[i] = *(const short8*)(base + row * K_DIM);                      \
        }                                                                      \
    }
// writes BOTH chunks of the granule: lane half selects destination buffer
#define WRITE_B2()                                                             \
    {                                                                          \
        char* bb = (char*)&Bbuf[0][0] + (lane >> 5) * BUFB;                    \
        _Pragma("unroll") for (int i = 0; i < 16; ++i) {                       \
            const int row = w * 16 + i;                                        \
            ushort4 h;                                                         \
            h.x = f2bf_trunc((float)aB[i][0]);                                 \
            h.y = f2bf_trunc((float)aB[i][1]);                                 \
            h.z = f2bf_trunc((float)aB[i][2]);                                 \
            h.w = f2bf_trunc((float)aB[i][3]);                                 \
            const int off = ((lane & 31) * 8) ^ ((row & 7) << 4);              \
            *(ushort4*)(bb + row * 256 + off) = h;                             \
        }                                                                      \
    }
#define WRITE_A2()                                                             \
    {                                                                          \
        char* ab = (char*)&Abuf[0][0] + ((lane & 31) >> 4) * BUFB;             \
        _Pragma("unroll") for (int i = 0; i < 8; ++i) {                        \
            const int row = w * 16 + i * 2 + (lane >> 5);                      \
            const int off = ((lane & 15) * 16) ^ ((row & 7) << 4);             \
            *(short8*)(ab + row * 256 + off) = aA[i];                          \
        }                                                                      \
    }
#define COMPUTE(bufi)                                                          \
    {                                                                          \
        _Pragma("unroll") for (int ks = 0; ks < 4; ++ks) {                     \
            const int swz = (ks * 64 + kgrp * 16) ^ ((r16 & 7) << 4);          \
            short8 bfrag = *(const short8*)(                                   \
                (char*)&Bbuf[bufi][(w * 16 + r16) * KSTEP] + swz);             \
            _Pragma("unroll") for (int mt = 0; mt < 4; ++mt) {                 \
                short8 afrag = *(const short8*)(                               \
                    (char*)&Abuf[bufi][(mt * 16 + r16) * KSTEP] + swz);        \
                acc[mt] = __builtin_amdgcn_mfma_f32_16x16x32_bf16(             \
                    afrag, bfrag, acc[mt], 0, 0, 0);                           \
            }                                                                  \
        }                                                                      \
    }

    f32x4 acc[4];
#pragma unroll
    for (int i = 0; i < 4; ++i) acc[i] = (f32x4){0.f, 0.f, 0.f, 0.f};

    // granule 0 prologue
    ISSUE_B2(0)
    ISSUE_A2(0)
    WRITE_B2()
    WRITE_A2()
    __syncthreads();
    ISSUE_B2(1)
    ISSUE_A2(1)
    COMPUTE(0)
    COMPUTE(1)
    __syncthreads();

    // granules 1 .. NGRAN-2: steady state
#pragma unroll
    for (int g = 1; g < NGRAN - 1; ++g) {
        WRITE_B2()
        WRITE_A2()
        ISSUE_B2(g + 1)
        ISSUE_A2(g + 1)
        __syncthreads();
        COMPUTE(0)
        COMPUTE(1)
        __syncthreads();
    }

    // final granule
    WRITE_B2()
    WRITE_A2()
    __syncthreads();
    COMPUTE(0)
    COMPUTE(1)

    // epilogue: C via LDS for coalesced partials write (verbatim)
    __syncthreads();
    float* Cl = (float*)&Abuf[0][0];  // [64 m][64 n] f32 = 16 KB
#pragma unroll
    for (int mt = 0; mt < 4; ++mt)
#pragma unroll
        for (int j = 0; j < 4; ++j)
            Cl[(mt * 16 + kgrp * 4 + j) * 64 + w * 16 + r16] = acc[mt][j];
    __syncthreads();
    float* pb = partials + (size_t)kb * (M_DIM * N_DIM);
#pragma unroll
    for (int i = 0; i < 4; ++i) {
        const int idx = tid + 256 * i;
        const int m = idx >> 4;
        const int ch = idx & 15;
        *(f32x4*)(pb + m * N_DIM + n0 + ch * 4) = ((const f32x4*)Cl)[idx];
    }
#undef ISSUE_B2
#undef ISSUE_A2
#undef WRITE_A2
#undef WRITE_B2
#undef COMPUTE
}

// ---------------- Kernel 3: split-K reduce + dequant + bias --------------------
__global__ __launch_bounds__(256) void reduce_kernel(
    const float* __restrict__ partials,
    const float* __restrict__ xscale,
    const float* __restrict__ wscale,
    const float* __restrict__ bias,
    float* __restrict__ out) {
    const int idx = blockIdx.x * 256 + threadIdx.x;  // 0 .. 64*2560-1
    const int m = idx / (N_DIM / 4);
    const int c = idx - m * (N_DIM / 4);
    const f32x4* P = (const f32x4*)partials;
    f32x4 s = (f32x4){0.f, 0.f, 0.f, 0.f};
#pragma unroll
    for (int p = 0; p < KSPLIT; ++p)
        s += P[((size_t)p * M_DIM + m) * (N_DIM / 4) + c];
    f32x4 ws = ((const f32x4*)wscale)[c];
    f32x4 bs = ((const f32x4*)bias)[c];
    const float xs = xscale[m];
    ((f32x4*)out)[idx] = s * xs * ws + bs;
}

extern "C" void kernel_launch(void* const* d_in, const int* in_sizes, int n_in,
                              void* d_out, int out_size, void* d_ws, size_t ws_size,
                              hipStream_t stream) {
    const float* x = (const float*)d_in[0];
    const int* W = (const int*)d_in[1];
    const float* wscale = (const float*)d_in[2];
    const float* bias = (const float*)d_in[3];
    float* out = (float*)d_out;

    float* xscale = (float*)d_ws;                       // 256 B
    ushort* xq = (ushort*)((char*)d_ws + 4096);         // 1 MB
    float* partials = (float*)((char*)d_ws + 2097152);  // 10.5 MB

    quant_kernel<<<M_DIM, 256, 0, stream>>>(x, xq, xscale);
    gemm_kernel<<<dim3(N_DIM / NTILE, KSPLIT), 256, 0, stream>>>(xq, W, partials);
    reduce_kernel<<<(M_DIM * N_DIM / 4) / 256, 256, 0, stream>>>(
        partials, xscale, wscale, bias, out);
}